// Round 1
// baseline (890.215 us; speedup 1.0000x reference)
//
#include <hip/hip_runtime.h>

#define DIM 2048
#define NTOK 65536

typedef float floatx4 __attribute__((ext_vector_type(4)));

// Extract lam[d] = -|W[d,d]| into workspace (8 KiB).
__global__ void diag_extract_kernel(const float* __restrict__ W,
                                    float* __restrict__ lam) {
    int d = blockIdx.x * blockDim.x + threadIdx.x;
    if (d < DIM) {
        lam[d] = -fabsf(W[(size_t)d * (DIM + 1)]);
    }
}

// out[n,d] = x[n,d] * lam[d].
// Grid-stride, 2048 blocks x 256 threads = 524288 threads (multiple of DIM/4),
// so each thread's lam float4 is loop-invariant -> hoisted to a register.
// Non-temporal loads/stores: x and out are stream-once, keep them out of L2/L3.
__global__ __launch_bounds__(256) void diag_scale_kernel(
    const floatx4* __restrict__ x,
    const floatx4* __restrict__ lam4,   // DIM/4 = 512 float4s
    floatx4* __restrict__ out,
    int n4) {
    const int nthreads = gridDim.x * blockDim.x;       // 524288, multiple of 512
    int i = blockIdx.x * blockDim.x + threadIdx.x;
    const floatx4 lv = lam4[i & (DIM / 4 - 1)];        // loop-invariant per thread

    // n4 = 33,554,432 ; trip count = n4 / 524288 = 64 exactly.
    #pragma unroll 4
    for (; i < n4; i += nthreads) {
        floatx4 xv = __builtin_nontemporal_load(&x[i]);
        __builtin_nontemporal_store(xv * lv, &out[i]);
    }
}

extern "C" void kernel_launch(void* const* d_in, const int* in_sizes, int n_in,
                              void* d_out, int out_size, void* d_ws, size_t ws_size,
                              hipStream_t stream) {
    const float* x = (const float*)d_in[0];
    const float* W = (const float*)d_in[1];
    float* out = (float*)d_out;
    float* lam = (float*)d_ws;  // 2048 floats = 8 KiB scratch

    // 1) extract diagonal (trivial: 128 KiB of strided reads, ~1 us)
    diag_extract_kernel<<<(DIM + 255) / 256, 256, 0, stream>>>(W, lam);

    // 2) elementwise scale: 2048 blocks = 8 blocks/CU on 256 CUs (full occupancy),
    //    grid-stride over 33.5M float4s.
    const int n4 = (NTOK * DIM) / 4;
    diag_scale_kernel<<<2048, 256, 0, stream>>>(
        (const floatx4*)x, (const floatx4*)lam, (floatx4*)out, n4);
}